// Round 13
// baseline (302.935 us; speedup 1.0000x reference)
//
#include <hip/hip_runtime.h>
#include <hip/hip_bf16.h>
#include <math.h>

#define N_NODES 50000
#define E_EDGES 800000
#define E_TOT   850000   // + self loops
#define NEG_SLOPE 0.2f
#define SCAN_BLOCKS 49   // ceil(50001/1024)
#define BUCKETS 512
#define RNG 98           // dst nodes per bucket (512*98 = 50176 >= 50000)
#define FA_CHUNK 16384   // edges per fillA workgroup
#define FA_THREADS 512
#define FA_EPT (FA_CHUNK / FA_THREADS)   // 32 edges/thread

// ---------------------------------------------------------------------------
// Fused: zero offs histogram + int64/int32 edge-index detection
// ---------------------------------------------------------------------------
__global__ __launch_bounds__(256) void k_detect0(const unsigned int* __restrict__ ei,
                                                 int* __restrict__ flag,
                                                 int* __restrict__ offs) {
    int gid = blockIdx.x * 256 + threadIdx.x;
    for (int i = gid; i <= N_NODES; i += gridDim.x * 256) offs[i] = 0;
    if (blockIdx.x == 0) {
        __shared__ int anynz;
        if (threadIdx.x == 0) anynz = 0;
        __syncthreads();
        int nz = 0;
        for (int i = threadIdx.x; i < 2048; i += 256)
            nz |= (ei[2 * i + 1] != 0u);
        if (nz) atomicOr(&anynz, 1);
        __syncthreads();
        if (threadIdx.x == 0) *flag = (anynz == 0) ? 1 : 0;
    }
}

__device__ __forceinline__ void edge_nodes(const void* ei, int is64, int e, int& s, int& d) {
    if (e >= E_EDGES) { s = d = e - E_EDGES; return; }   // self loop
    if (is64) {
        const long long* p = (const long long*)ei;
        s = (int)p[e]; d = (int)p[E_EDGES + e];
    } else {
        const int* p = (const int*)ei;
        s = p[e]; d = p[E_EDGES + e];
    }
}

// ---------------------------------------------------------------------------
// CSR build: histogram -> parallel scan -> bucketed two-phase fill
// ---------------------------------------------------------------------------
__global__ void k_count(const void* __restrict__ ei, const int* __restrict__ flag,
                        int* __restrict__ counts) {
    int e = blockIdx.x * 256 + threadIdx.x;
    if (e >= E_TOT) return;
    int d;
    if (e >= E_EDGES) d = e - E_EDGES;
    else if (*flag)   d = (int)((const long long*)ei)[E_EDGES + e];
    else              d = ((const int*)ei)[E_EDGES + e];
    atomicAdd(&counts[d], 1);
}

// block-local exclusive scan (in place) + per-block total
__global__ __launch_bounds__(1024) void k_scanA(int* __restrict__ offs,
                                                int* __restrict__ partials) {
    __shared__ int lds[1024];
    const int t   = threadIdx.x;
    const int idx = blockIdx.x * 1024 + t;
    int v = (idx <= N_NODES) ? offs[idx] : 0;
    lds[t] = v;
    __syncthreads();
    for (int off = 1; off < 1024; off <<= 1) {
        int u = (t >= off) ? lds[t - off] : 0;
        __syncthreads();
        lds[t] += u;
        __syncthreads();
    }
    int incl = lds[t];
    if (idx <= N_NODES) offs[idx] = incl - v;         // exclusive within chunk
    if (t == 1023) partials[blockIdx.x] = incl;       // chunk total
}

// add scanned partials prefix; emit final offs + cursor copy + bucket cursors
__global__ __launch_bounds__(1024) void k_scanC(int* __restrict__ offs,
                                                const int* __restrict__ partials,
                                                int* __restrict__ cursor,
                                                int* __restrict__ bcur) {
    __shared__ int sprefix;
    const int t   = threadIdx.x;
    const int bid = blockIdx.x;
    if (t < 64) {
        int p = (t < bid) ? partials[t] : 0;          // bid <= 48 < 64
#pragma unroll
        for (int off = 32; off; off >>= 1) p += __shfl_down(p, off);
        if (t == 0) sprefix = p;
    }
    __syncthreads();
    const int idx = bid * 1024 + t;
    if (idx <= N_NODES) {
        int v = offs[idx] + sprefix;
        offs[idx] = v;
        if (idx < N_NODES) cursor[idx] = v;
        if ((idx % RNG) == 0 && idx < N_NODES) bcur[idx / RNG] = v;   // b = 0..510
        if (idx == N_NODES) bcur[BUCKETS - 1] = v;                    // unused, safe init
    }
}

// phase A: LDS-binned staging. Each wg: 16K edges -> 512 bucket runs.
__global__ __launch_bounds__(FA_THREADS) void k_fillA(const void* __restrict__ ei,
                                                      const int* __restrict__ flag,
                                                      int* __restrict__ bcur,
                                                      unsigned int* __restrict__ stage) {
    __shared__ int cnt[BUCKETS];
    __shared__ int base[BUCKETS];
    __shared__ int lofs[BUCKETS];
    const int t  = threadIdx.x;
    const int cb = blockIdx.x * FA_CHUNK;
    const int is64 = *flag;
    cnt[t] = 0;
    __syncthreads();
    unsigned int pk[FA_EPT];
#pragma unroll
    for (int i = 0; i < FA_EPT; ++i) {
        int e = cb + i * FA_THREADS + t;
        pk[i] = 0xFFFFFFFFu;
        if (e < E_TOT) {
            int s, d;
            edge_nodes(ei, is64, e, s, d);
            pk[i] = ((unsigned)d << 16) | (unsigned)s;
            atomicAdd(&cnt[(unsigned)d / RNG], 1);
        }
    }
    __syncthreads();
    {
        int c = cnt[t];
        base[t] = c ? atomicAdd(&bcur[t], c) : 0;
        lofs[t] = 0;
    }
    __syncthreads();
#pragma unroll
    for (int i = 0; i < FA_EPT; ++i) {
        if (pk[i] != 0xFFFFFFFFu) {
            int b  = (pk[i] >> 16) / RNG;
            int lp = atomicAdd(&lofs[b], 1);
            stage[base[b] + lp] = pk[i];
        }
    }
}

// phase B: per-bucket reorder into exact dst-grouped csr (wg-local window).
__global__ __launch_bounds__(256) void k_fillB(const unsigned int* __restrict__ stage,
                                               const int* __restrict__ offs,
                                               int* __restrict__ cursor,
                                               int* __restrict__ csr) {
    const int b = blockIdx.x;
    const int t = threadIdx.x;
    if (b == 0 && t < 16) csr[E_TOT + t] = 0;          // pad (valid node id 0)
    const int lo  = b * RNG;
    const int hi  = min(lo + RNG, N_NODES);
    const int rb0 = offs[lo];
    const int rb1 = offs[hi];
    for (int i = rb0 + t; i < rb1; i += 256) {
        unsigned int v = stage[i];
        int d   = (int)(v >> 16);
        int pos = atomicAdd(&cursor[d], 1);
        csr[pos] = (int)(v & 0xFFFFu);
    }
}

// ---------------------------------------------------------------------------
// K1: h1 = x @ W1 (50000x128 @ 128x64) + per-node attention halves
// ---------------------------------------------------------------------------
__global__ __launch_bounds__(256) void k1_transform(
        const float* __restrict__ x, const float* __restrict__ W1,
        const float* __restrict__ a1s, const float* __restrict__ a1d,
        float* __restrict__ h1, float* __restrict__ as1, float* __restrict__ ad1) {
    __shared__ float ws[128 * 64];
    __shared__ float xs[64 * 132];
    const int t  = threadIdx.x;
    const int nb = blockIdx.x * 64;
    for (int i = t * 4; i < 128 * 64; i += 1024)
        *(float4*)&ws[i] = *(const float4*)&W1[i];
    for (int i = t * 4; i < 64 * 128; i += 1024) {
        int n = i >> 7, k = i & 127;
        float4 v = make_float4(0.f, 0.f, 0.f, 0.f);
        if (nb + n < N_NODES) v = *(const float4*)&x[(size_t)(nb + n) * 128 + k];
        *(float4*)&xs[n * 132 + k] = v;
    }
    __syncthreads();

    const int oq = t & 15;
    const int nq = t >> 4;
    float4 acc[4];
#pragma unroll
    for (int i = 0; i < 4; ++i) acc[i] = make_float4(0.f, 0.f, 0.f, 0.f);

    for (int k = 0; k < 128; k += 4) {
        float4 wv0 = *(float4*)&ws[(k + 0) * 64 + oq * 4];
        float4 wv1 = *(float4*)&ws[(k + 1) * 64 + oq * 4];
        float4 wv2 = *(float4*)&ws[(k + 2) * 64 + oq * 4];
        float4 wv3 = *(float4*)&ws[(k + 3) * 64 + oq * 4];
#pragma unroll
        for (int i = 0; i < 4; ++i) {
            float4 xv = *(float4*)&xs[(nq * 4 + i) * 132 + k];
            acc[i].x += xv.x * wv0.x + xv.y * wv1.x + xv.z * wv2.x + xv.w * wv3.x;
            acc[i].y += xv.x * wv0.y + xv.y * wv1.y + xv.z * wv2.y + xv.w * wv3.y;
            acc[i].z += xv.x * wv0.z + xv.y * wv1.z + xv.z * wv2.z + xv.w * wv3.z;
            acc[i].w += xv.x * wv0.w + xv.y * wv1.w + xv.z * wv2.w + xv.w * wv3.w;
        }
    }
    __syncthreads();
#pragma unroll
    for (int i = 0; i < 4; ++i) {
        int n = nq * 4 + i;
        *(float4*)&xs[n * 68 + oq * 4] = acc[i];
        if (nb + n < N_NODES)
            *(float4*)&h1[(size_t)(nb + n) * 64 + oq * 4] = acc[i];
    }
    __syncthreads();
    for (int p = t; p < 512; p += 256) {
        int n = p >> 3, hd = p & 7;
        float ss = 0.f, dd = 0.f;
#pragma unroll
        for (int o = 0; o < 8; ++o) {
            float hv = xs[n * 68 + hd * 8 + o];
            ss += hv * a1s[hd * 8 + o];
            dd += hv * a1d[hd * 8 + o];
        }
        if (nb + n < N_NODES) {
            as1[(nb + n) * 8 + hd] = ss;
            ad1[(nb + n) * 8 + hd] = dd;
        }
    }
}

// ---------------------------------------------------------------------------
// K_agg1 (fused with layer-2 transform).
// Lane layout: q = l>>4 (edge slot 0..3), r = l&15 (feature quad), h = r>>1.
// 4 edges per iteration, one float4 h1 load per lane, one exp per lane.
// Cross-lane fold over q at the end (shfl_xor 16,32).
// ---------------------------------------------------------------------------
__global__ __launch_bounds__(256) void k_agg1f(
        const float* __restrict__ h1, const float* __restrict__ as1g,
        const float* __restrict__ ad1g, const int* __restrict__ offs,
        const int* __restrict__ csr, const float* __restrict__ b1,
        const float* __restrict__ W2, const float* __restrict__ a2s,
        const float* __restrict__ a2d,
        float* __restrict__ h2p, float* __restrict__ as2, float* __restrict__ ad2) {
    __shared__ float ws[64 * 40];            // 10 KB
    __shared__ float rows[4][64];
    const int t = threadIdx.x;
    for (int i = t; i < 64 * 40; i += 256) ws[i] = W2[i];
    __syncthreads();

    const int w = t >> 6, l = t & 63;
    const int q = l >> 4;                    // edge slot
    const int r = l & 15;                    // feature quad
    const int h = r >> 1;                    // head
    const int wid = blockIdx.x * 4 + w;
    if (wid >= N_NODES) return;
    const float ad = ad1g[wid * 8 + h];
    const int j0 = __builtin_amdgcn_readfirstlane(offs[wid]);
    const int j1 = __builtin_amdgcn_readfirstlane(offs[wid + 1]);

    float den = 0.f;
    float4 acc = make_float4(0.f, 0.f, 0.f, 0.f);

    int c = csr[j0 + q];                                          // pad-safe
    float  a = as1g[(unsigned)c * 8u + (unsigned)h];
    float4 g = *(const float4*)&h1[(unsigned)c * 64u + (unsigned)r * 4u];
    int cn = csr[j0 + 4 + q];                                     // pad-safe
    int j = j0;
    while (j + 4 <= j1) {                    // full groups, no predication
        float  an = as1g[(unsigned)cn * 8u + (unsigned)h];
        float4 gn = *(const float4*)&h1[(unsigned)cn * 64u + (unsigned)r * 4u];
        int cnn = csr[j + 8 + q];                                 // pad-safe
        float e = a + ad;
        e = fmaxf(e, NEG_SLOPE * e);
        float xp = __expf(e);
        den += xp;
        acc.x = fmaf(xp, g.x, acc.x);
        acc.y = fmaf(xp, g.y, acc.y);
        acc.z = fmaf(xp, g.z, acc.z);
        acc.w = fmaf(xp, g.w, acc.w);
        a = an; g = gn; cn = cnn;
        j += 4;
    }
    const int rem = j1 - j;                  // 0..3 (values already resident)
    if (rem) {
        float e = a + ad;
        e = fmaxf(e, NEG_SLOPE * e);
        float xp = (q < rem) ? __expf(e) : 0.f;
        den += xp;
        acc.x = fmaf(xp, g.x, acc.x);
        acc.y = fmaf(xp, g.y, acc.y);
        acc.z = fmaf(xp, g.z, acc.z);
        acc.w = fmaf(xp, g.w, acc.w);
    }
    // fold edge slots q (lane ^16, ^32)
#pragma unroll
    for (int m = 16; m <= 32; m <<= 1) {
        den   += __shfl_xor(den,   m);
        acc.x += __shfl_xor(acc.x, m);
        acc.y += __shfl_xor(acc.y, m);
        acc.z += __shfl_xor(acc.z, m);
        acc.w += __shfl_xor(acc.w, m);
    }
    const float inv = 1.0f / den;
    float4 bv = *(const float4*)&b1[r * 4];
    float4 v;
    v.x = fmaf(acc.x, inv, bv.x);
    v.y = fmaf(acc.y, inv, bv.y);
    v.z = fmaf(acc.z, inv, bv.z);
    v.w = fmaf(acc.w, inv, bv.w);
    v.x = (v.x > 0.f) ? v.x : expm1f(v.x);   // ELU
    v.y = (v.y > 0.f) ? v.y : expm1f(v.y);
    v.z = (v.z > 0.f) ? v.z : expm1f(v.z);
    v.w = (v.w > 0.f) ? v.w : expm1f(v.w);
    if (q == 0) *(float4*)&rows[w][r * 4] = v;   // wave-private exchange

    float acc2 = 0.f;
    if (l < 40) {
#pragma unroll 8
        for (int k = 0; k < 64; ++k)
            acc2 = fmaf(rows[w][k], ws[k * 40 + l], acc2);
    }
    float ps = (l < 40) ? acc2 * a2s[l] : 0.f;
    float pd = (l < 40) ? acc2 * a2d[l] : 0.f;
#pragma unroll
    for (int off = 32; off; off >>= 1) {
        ps += __shfl_down(ps, off);
        pd += __shfl_down(pd, off);
    }
    if (l < 40) h2p[(unsigned)wid * 48u + (unsigned)l] = acc2;
    if (l == 0) { as2[wid] = ps; ad2[wid] = pd; }
}

// ---------------------------------------------------------------------------
// K_agg2: same 4-edge packed structure; 40 feats on r<10; log_softmax via
// 4-component + 4-round shfl reduce; float4 output stores.
// ---------------------------------------------------------------------------
__global__ __launch_bounds__(256) void k_agg2(
        const float* __restrict__ h2p, const float* __restrict__ as2,
        const float* __restrict__ ad2, const int* __restrict__ offs,
        const int* __restrict__ csr, const float* __restrict__ b2,
        float* __restrict__ out) {
    int wid = (blockIdx.x * 256 + threadIdx.x) >> 6;
    int l   = threadIdx.x & 63;
    if (wid >= N_NODES) return;
    const int q = l >> 4;
    const int r = l & 15;
    const bool act = (r < 10);
    const float ad = ad2[wid];
    const int j0 = __builtin_amdgcn_readfirstlane(offs[wid]);
    const int j1 = __builtin_amdgcn_readfirstlane(offs[wid + 1]);

    float den = 0.f;
    float4 acc = make_float4(0.f, 0.f, 0.f, 0.f);

    int c = csr[j0 + q];
    float  a = as2[c];
    float4 g = act ? *(const float4*)&h2p[(unsigned)c * 48u + (unsigned)r * 4u]
                   : make_float4(0.f, 0.f, 0.f, 0.f);
    int cn = csr[j0 + 4 + q];
    int j = j0;
    while (j + 4 <= j1) {
        float  an = as2[cn];
        float4 gn = act ? *(const float4*)&h2p[(unsigned)cn * 48u + (unsigned)r * 4u]
                        : make_float4(0.f, 0.f, 0.f, 0.f);
        int cnn = csr[j + 8 + q];
        float e = a + ad;
        e = fmaxf(e, NEG_SLOPE * e);
        float xp = __expf(e);
        den += xp;
        acc.x = fmaf(xp, g.x, acc.x);
        acc.y = fmaf(xp, g.y, acc.y);
        acc.z = fmaf(xp, g.z, acc.z);
        acc.w = fmaf(xp, g.w, acc.w);
        a = an; g = gn; cn = cnn;
        j += 4;
    }
    const int rem = j1 - j;
    if (rem) {
        float e = a + ad;
        e = fmaxf(e, NEG_SLOPE * e);
        float xp = (q < rem) ? __expf(e) : 0.f;
        den += xp;
        acc.x = fmaf(xp, g.x, acc.x);
        acc.y = fmaf(xp, g.y, acc.y);
        acc.z = fmaf(xp, g.z, acc.z);
        acc.w = fmaf(xp, g.w, acc.w);
    }
#pragma unroll
    for (int m = 16; m <= 32; m <<= 1) {
        den   += __shfl_xor(den,   m);
        acc.x += __shfl_xor(acc.x, m);
        acc.y += __shfl_xor(acc.y, m);
        acc.z += __shfl_xor(acc.z, m);
        acc.w += __shfl_xor(acc.w, m);
    }
    const float inv = 1.0f / den;
    float4 v = make_float4(0.f, 0.f, 0.f, 0.f);
    if (act) {
        float4 bv = *(const float4*)&b2[r * 4];
        v.x = fmaf(acc.x, inv, bv.x);
        v.y = fmaf(acc.y, inv, bv.y);
        v.z = fmaf(acc.z, inv, bv.z);
        v.w = fmaf(acc.w, inv, bv.w);
    }
    // log_softmax over 40 values spread on r=0..9 x 4 components
    float mx = act ? fmaxf(fmaxf(v.x, v.y), fmaxf(v.z, v.w)) : -1e30f;
#pragma unroll
    for (int m = 1; m <= 8; m <<= 1) mx = fmaxf(mx, __shfl_xor(mx, m));
    float s = act ? (__expf(v.x - mx) + __expf(v.y - mx) +
                     __expf(v.z - mx) + __expf(v.w - mx)) : 0.f;
#pragma unroll
    for (int m = 1; m <= 8; m <<= 1) s += __shfl_xor(s, m);
    const float lg = mx + __logf(s);
    if (act && q == 0) {
        float4 o;
        o.x = v.x - lg; o.y = v.y - lg; o.z = v.z - lg; o.w = v.w - lg;
        *(float4*)&out[(size_t)wid * 40 + r * 4] = o;
    }
}

// ---------------------------------------------------------------------------
extern "C" void kernel_launch(void* const* d_in, const int* in_sizes, int n_in,
                              void* d_out, int out_size, void* d_ws, size_t ws_size,
                              hipStream_t stream) {
    const float* x   = (const float*)d_in[0];
    const void*  ei  = d_in[1];
    const float* W1  = (const float*)d_in[2];
    const float* a1s = (const float*)d_in[3];
    const float* a1d = (const float*)d_in[4];
    const float* b1  = (const float*)d_in[5];
    const float* W2  = (const float*)d_in[6];
    const float* a2s = (const float*)d_in[7];
    const float* a2d = (const float*)d_in[8];
    const float* b2  = (const float*)d_in[9];
    float* out = (float*)d_out;

    // workspace layout (floats)
    float* fws = (float*)d_ws;
    float* h1  = fws + 0;                     // 3,200,000
    float* as1 = fws + 3200000;               //   400,000
    float* ad1 = fws + 3600000;               //   400,000
    float* h2p = fws + 4000000;               // 2,400,000 (stride 48)
    float* as2 = fws + 6400000;               //    50,000
    float* ad2 = fws + 6450000;               //    50,000
    int*   offs     = (int*)(fws + 6500000);  // 50,001
    int*   cursor   = offs + (N_NODES + 1);   // 50,000
    int*   csr      = cursor + N_NODES;       // 850,000 + 16 pad
    int*   partials = csr + E_TOT + 16;       // 49
    int*   flag     = partials + SCAN_BLOCKS; // 1
    int*   bcur     = flag + 1;               // 512
    unsigned int* stage = (unsigned int*)(bcur + BUCKETS);  // 850,000

    k_detect0<<<64, 256, 0, stream>>>((const unsigned int*)ei, flag, offs);

    int egrid = (E_TOT + 255) / 256;
    k_count<<<egrid, 256, 0, stream>>>(ei, flag, offs);
    k_scanA<<<SCAN_BLOCKS, 1024, 0, stream>>>(offs, partials);
    k_scanC<<<SCAN_BLOCKS, 1024, 0, stream>>>(offs, partials, cursor, bcur);

    int fagrid = (E_TOT + FA_CHUNK - 1) / FA_CHUNK;   // 52
    k_fillA<<<fagrid, FA_THREADS, 0, stream>>>(ei, flag, bcur, stage);
    k_fillB<<<BUCKETS - 1, 256, 0, stream>>>(stage, offs, cursor, csr);

    k1_transform<<<(N_NODES + 63) / 64, 256, 0, stream>>>(x, W1, a1s, a1d, h1, as1, ad1);

    int ngrid = (N_NODES + 3) / 4;
    k_agg1f<<<ngrid, 256, 0, stream>>>(h1, as1, ad1, offs, csr, b1,
                                       W2, a2s, a2d, h2p, as2, ad2);
    k_agg2<<<ngrid, 256, 0, stream>>>(h2p, as2, ad2, offs, csr, b2, out);
}

// Round 15
// 302.096 us; speedup vs baseline: 1.0028x; 1.0028x over previous
//
#include <hip/hip_runtime.h>
#include <hip/hip_bf16.h>
#include <math.h>

#define N_NODES 50000
#define E_EDGES 800000
#define E_TOT   850000   // + self loops
#define NEG_SLOPE 0.2f
#define SCAN_BLOCKS 49   // ceil(50001/1024)
#define BUCKETS 512
#define RNG 98           // dst nodes per bucket (512*98 = 50176 >= 50000)
#define FA_CHUNK 16384   // edges per fillA workgroup
#define FA_THREADS 512
#define FA_EPT (FA_CHUNK / FA_THREADS)   // 32 edges/thread

// ---------------------------------------------------------------------------
// Fused: zero offs histogram + int64/int32 edge-index detection
// ---------------------------------------------------------------------------
__global__ __launch_bounds__(256) void k_detect0(const unsigned int* __restrict__ ei,
                                                 int* __restrict__ flag,
                                                 int* __restrict__ offs) {
    int gid = blockIdx.x * 256 + threadIdx.x;
    for (int i = gid; i <= N_NODES; i += gridDim.x * 256) offs[i] = 0;
    if (blockIdx.x == 0) {
        __shared__ int anynz;
        if (threadIdx.x == 0) anynz = 0;
        __syncthreads();
        int nz = 0;
        for (int i = threadIdx.x; i < 2048; i += 256)
            nz |= (ei[2 * i + 1] != 0u);
        if (nz) atomicOr(&anynz, 1);
        __syncthreads();
        if (threadIdx.x == 0) *flag = (anynz == 0) ? 1 : 0;
    }
}

__device__ __forceinline__ void edge_nodes(const void* ei, int is64, int e, int& s, int& d) {
    if (e >= E_EDGES) { s = d = e - E_EDGES; return; }   // self loop
    if (is64) {
        const long long* p = (const long long*)ei;
        s = (int)p[e]; d = (int)p[E_EDGES + e];
    } else {
        const int* p = (const int*)ei;
        s = p[e]; d = p[E_EDGES + e];
    }
}

// ---------------------------------------------------------------------------
// CSR build: histogram -> parallel scan -> bucketed two-phase fill
// ---------------------------------------------------------------------------
__global__ void k_count(const void* __restrict__ ei, const int* __restrict__ flag,
                        int* __restrict__ counts) {
    int e = blockIdx.x * 256 + threadIdx.x;
    if (e >= E_TOT) return;
    int d;
    if (e >= E_EDGES) d = e - E_EDGES;
    else if (*flag)   d = (int)((const long long*)ei)[E_EDGES + e];
    else              d = ((const int*)ei)[E_EDGES + e];
    atomicAdd(&counts[d], 1);
}

// block-local exclusive scan (in place) + per-block total
__global__ __launch_bounds__(1024) void k_scanA(int* __restrict__ offs,
                                                int* __restrict__ partials) {
    __shared__ int lds[1024];
    const int t   = threadIdx.x;
    const int idx = blockIdx.x * 1024 + t;
    int v = (idx <= N_NODES) ? offs[idx] : 0;
    lds[t] = v;
    __syncthreads();
    for (int off = 1; off < 1024; off <<= 1) {
        int u = (t >= off) ? lds[t - off] : 0;
        __syncthreads();
        lds[t] += u;
        __syncthreads();
    }
    int incl = lds[t];
    if (idx <= N_NODES) offs[idx] = incl - v;         // exclusive within chunk
    if (t == 1023) partials[blockIdx.x] = incl;       // chunk total
}

// add scanned partials prefix; emit final offs + cursor copy + bucket cursors
__global__ __launch_bounds__(1024) void k_scanC(int* __restrict__ offs,
                                                const int* __restrict__ partials,
                                                int* __restrict__ cursor,
                                                int* __restrict__ bcur) {
    __shared__ int sprefix;
    const int t   = threadIdx.x;
    const int bid = blockIdx.x;
    if (t < 64) {
        int p = (t < bid) ? partials[t] : 0;          // bid <= 48 < 64
#pragma unroll
        for (int off = 32; off; off >>= 1) p += __shfl_down(p, off);
        if (t == 0) sprefix = p;
    }
    __syncthreads();
    const int idx = bid * 1024 + t;
    if (idx <= N_NODES) {
        int v = offs[idx] + sprefix;
        offs[idx] = v;
        if (idx < N_NODES) cursor[idx] = v;
        if ((idx % RNG) == 0 && idx < N_NODES) bcur[idx / RNG] = v;   // b = 0..510
        if (idx == N_NODES) bcur[BUCKETS - 1] = v;                    // unused, safe init
    }
}

// phase A: LDS-binned staging. Each wg: 16K edges -> 512 bucket runs.
__global__ __launch_bounds__(FA_THREADS) void k_fillA(const void* __restrict__ ei,
                                                      const int* __restrict__ flag,
                                                      int* __restrict__ bcur,
                                                      unsigned int* __restrict__ stage) {
    __shared__ int cnt[BUCKETS];
    __shared__ int base[BUCKETS];
    __shared__ int lofs[BUCKETS];
    const int t  = threadIdx.x;
    const int cb = blockIdx.x * FA_CHUNK;
    const int is64 = *flag;
    cnt[t] = 0;
    __syncthreads();
    unsigned int pk[FA_EPT];
#pragma unroll
    for (int i = 0; i < FA_EPT; ++i) {
        int e = cb + i * FA_THREADS + t;
        pk[i] = 0xFFFFFFFFu;
        if (e < E_TOT) {
            int s, d;
            edge_nodes(ei, is64, e, s, d);
            pk[i] = ((unsigned)d << 16) | (unsigned)s;
            atomicAdd(&cnt[(unsigned)d / RNG], 1);
        }
    }
    __syncthreads();
    {
        int c = cnt[t];
        base[t] = c ? atomicAdd(&bcur[t], c) : 0;
        lofs[t] = 0;
    }
    __syncthreads();
#pragma unroll
    for (int i = 0; i < FA_EPT; ++i) {
        if (pk[i] != 0xFFFFFFFFu) {
            int b  = (pk[i] >> 16) / RNG;
            int lp = atomicAdd(&lofs[b], 1);
            stage[base[b] + lp] = pk[i];
        }
    }
}

// phase B: per-bucket reorder into exact dst-grouped csr (wg-local window).
__global__ __launch_bounds__(256) void k_fillB(const unsigned int* __restrict__ stage,
                                               const int* __restrict__ offs,
                                               int* __restrict__ cursor,
                                               int* __restrict__ csr) {
    const int b = blockIdx.x;
    const int t = threadIdx.x;
    if (b == 0 && t < 16) csr[E_TOT + t] = 0;          // pad (valid node id 0)
    const int lo  = b * RNG;
    const int hi  = min(lo + RNG, N_NODES);
    const int rb0 = offs[lo];
    const int rb1 = offs[hi];
    for (int i = rb0 + t; i < rb1; i += 256) {
        unsigned int v = stage[i];
        int d   = (int)(v >> 16);
        int pos = atomicAdd(&cursor[d], 1);
        csr[pos] = (int)(v & 0xFFFFu);
    }
}

// ---------------------------------------------------------------------------
// K1: h1 = x @ W1 (50000x128 @ 128x64) + per-node attention halves
// ---------------------------------------------------------------------------
__global__ __launch_bounds__(256) void k1_transform(
        const float* __restrict__ x, const float* __restrict__ W1,
        const float* __restrict__ a1s, const float* __restrict__ a1d,
        float* __restrict__ h1, float* __restrict__ as1, float* __restrict__ ad1) {
    __shared__ float ws[128 * 64];
    __shared__ float xs[64 * 132];
    const int t  = threadIdx.x;
    const int nb = blockIdx.x * 64;
    for (int i = t * 4; i < 128 * 64; i += 1024)
        *(float4*)&ws[i] = *(const float4*)&W1[i];
    for (int i = t * 4; i < 64 * 128; i += 1024) {
        int n = i >> 7, k = i & 127;
        float4 v = make_float4(0.f, 0.f, 0.f, 0.f);
        if (nb + n < N_NODES) v = *(const float4*)&x[(size_t)(nb + n) * 128 + k];
        *(float4*)&xs[n * 132 + k] = v;
    }
    __syncthreads();

    const int oq = t & 15;
    const int nq = t >> 4;
    float4 acc[4];
#pragma unroll
    for (int i = 0; i < 4; ++i) acc[i] = make_float4(0.f, 0.f, 0.f, 0.f);

    for (int k = 0; k < 128; k += 4) {
        float4 wv0 = *(float4*)&ws[(k + 0) * 64 + oq * 4];
        float4 wv1 = *(float4*)&ws[(k + 1) * 64 + oq * 4];
        float4 wv2 = *(float4*)&ws[(k + 2) * 64 + oq * 4];
        float4 wv3 = *(float4*)&ws[(k + 3) * 64 + oq * 4];
#pragma unroll
        for (int i = 0; i < 4; ++i) {
            float4 xv = *(float4*)&xs[(nq * 4 + i) * 132 + k];
            acc[i].x += xv.x * wv0.x + xv.y * wv1.x + xv.z * wv2.x + xv.w * wv3.x;
            acc[i].y += xv.x * wv0.y + xv.y * wv1.y + xv.z * wv2.y + xv.w * wv3.y;
            acc[i].z += xv.x * wv0.z + xv.y * wv1.z + xv.z * wv2.z + xv.w * wv3.z;
            acc[i].w += xv.x * wv0.w + xv.y * wv1.w + xv.z * wv2.w + xv.w * wv3.w;
        }
    }
    __syncthreads();
#pragma unroll
    for (int i = 0; i < 4; ++i) {
        int n = nq * 4 + i;
        *(float4*)&xs[n * 68 + oq * 4] = acc[i];
        if (nb + n < N_NODES)
            *(float4*)&h1[(size_t)(nb + n) * 64 + oq * 4] = acc[i];
    }
    __syncthreads();
    for (int p = t; p < 512; p += 256) {
        int n = p >> 3, hd = p & 7;
        float ss = 0.f, dd = 0.f;
#pragma unroll
        for (int o = 0; o < 8; ++o) {
            float hv = xs[n * 68 + hd * 8 + o];
            ss += hv * a1s[hd * 8 + o];
            dd += hv * a1d[hd * 8 + o];
        }
        if (nb + n < N_NODES) {
            as1[(nb + n) * 8 + hd] = ss;
            ad1[(nb + n) * 8 + hd] = dd;
        }
    }
}

// ---------------------------------------------------------------------------
// K_agg1 (fused with layer-2 transform).
// Lane layout: q = l>>4 (edge slot 0..3), r = l&15 (feature quad), h = r>>1.
// 2-deep value pipeline: groups j and j+4 resident in regs, indices 3 ahead.
// 8 edges' gathers in flight; 1 exp per (edge,head) lane; float4 h1 loads.
// ---------------------------------------------------------------------------
__global__ __launch_bounds__(256) void k_agg1f(
        const float* __restrict__ h1, const float* __restrict__ as1g,
        const float* __restrict__ ad1g, const int* __restrict__ offs,
        const int* __restrict__ csr, const float* __restrict__ b1,
        const float* __restrict__ W2, const float* __restrict__ a2s,
        const float* __restrict__ a2d,
        float* __restrict__ h2p, float* __restrict__ as2, float* __restrict__ ad2) {
    __shared__ float ws[64 * 40];            // 10 KB
    __shared__ float rows[4][64];
    const int t = threadIdx.x;
    for (int i = t; i < 64 * 40; i += 256) ws[i] = W2[i];
    __syncthreads();

    const int w = t >> 6, l = t & 63;
    const int q = l >> 4;                    // edge slot
    const int r = l & 15;                    // feature quad
    const int h = r >> 1;                    // head
    const int wid = blockIdx.x * 4 + w;
    if (wid >= N_NODES) return;
    const float ad = ad1g[wid * 8 + h];
    const int j0 = __builtin_amdgcn_readfirstlane(offs[wid]);
    const int j1 = __builtin_amdgcn_readfirstlane(offs[wid + 1]);

    float den = 0.f;
    float4 acc = make_float4(0.f, 0.f, 0.f, 0.f);

    // prologue: values of groups j0 and j0+4 in flight; index of group j0+8
    int c0 = csr[j0 + q];                    // pad-safe (16-entry pad)
    int c1 = csr[j0 + 4 + q];
    int c2 = csr[j0 + 8 + q];
    float  aA = as1g[(unsigned)c0 * 8u + (unsigned)h];
    float4 gA = *(const float4*)&h1[(unsigned)c0 * 64u + (unsigned)r * 4u];
    float  aB = as1g[(unsigned)c1 * 8u + (unsigned)h];
    float4 gB = *(const float4*)&h1[(unsigned)c1 * 64u + (unsigned)r * 4u];

    int j = j0;
    while (j + 4 <= j1) {                    // full groups, no predication
        float e = aA + ad;
        e = fmaxf(e, NEG_SLOPE * e);
        float xp = __expf(e);
        den += xp;
        acc.x = fmaf(xp, gA.x, acc.x);
        acc.y = fmaf(xp, gA.y, acc.y);
        acc.z = fmaf(xp, gA.z, acc.z);
        acc.w = fmaf(xp, gA.w, acc.w);
        // rotate pipeline: A <- B, B <- values(c2), c2 <- index of group j+12
        aA = aB; gA = gB;
        aB = as1g[(unsigned)c2 * 8u + (unsigned)h];
        gB = *(const float4*)&h1[(unsigned)c2 * 64u + (unsigned)r * 4u];
        c2 = csr[j + 12 + q];                // max j1+14 < E_TOT+16: pad-safe
        j += 4;
    }
    const int rem = j1 - j;                  // 0..3; values for group j in A
    if (rem) {
        float e = aA + ad;
        e = fmaxf(e, NEG_SLOPE * e);
        float xp = (q < rem) ? __expf(e) : 0.f;
        den += xp;
        acc.x = fmaf(xp, gA.x, acc.x);
        acc.y = fmaf(xp, gA.y, acc.y);
        acc.z = fmaf(xp, gA.z, acc.z);
        acc.w = fmaf(xp, gA.w, acc.w);
    }
    // fold edge slots q (lane ^16, ^32)
#pragma unroll
    for (int m = 16; m <= 32; m <<= 1) {
        den   += __shfl_xor(den,   m);
        acc.x += __shfl_xor(acc.x, m);
        acc.y += __shfl_xor(acc.y, m);
        acc.z += __shfl_xor(acc.z, m);
        acc.w += __shfl_xor(acc.w, m);
    }
    const float inv = 1.0f / den;
    float4 bv = *(const float4*)&b1[r * 4];
    float4 v;
    v.x = fmaf(acc.x, inv, bv.x);
    v.y = fmaf(acc.y, inv, bv.y);
    v.z = fmaf(acc.z, inv, bv.z);
    v.w = fmaf(acc.w, inv, bv.w);
    v.x = (v.x > 0.f) ? v.x : expm1f(v.x);   // ELU
    v.y = (v.y > 0.f) ? v.y : expm1f(v.y);
    v.z = (v.z > 0.f) ? v.z : expm1f(v.z);
    v.w = (v.w > 0.f) ? v.w : expm1f(v.w);
    if (q == 0) *(float4*)&rows[w][r * 4] = v;   // wave-private exchange

    float acc2 = 0.f;
    if (l < 40) {
#pragma unroll 8
        for (int k = 0; k < 64; ++k)
            acc2 = fmaf(rows[w][k], ws[k * 40 + l], acc2);
    }
    float ps = (l < 40) ? acc2 * a2s[l] : 0.f;
    float pd = (l < 40) ? acc2 * a2d[l] : 0.f;
#pragma unroll
    for (int off = 32; off; off >>= 1) {
        ps += __shfl_down(ps, off);
        pd += __shfl_down(pd, off);
    }
    if (l < 40) h2p[(unsigned)wid * 48u + (unsigned)l] = acc2;
    if (l == 0) { as2[wid] = ps; ad2[wid] = pd; }
}

// ---------------------------------------------------------------------------
// K_agg2: same packed layout + 2-deep pipeline; 40 feats on r<10;
// log_softmax via 4-component + 4-round shfl reduce; float4 output stores.
// ---------------------------------------------------------------------------
__global__ __launch_bounds__(256) void k_agg2(
        const float* __restrict__ h2p, const float* __restrict__ as2,
        const float* __restrict__ ad2, const int* __restrict__ offs,
        const int* __restrict__ csr, const float* __restrict__ b2,
        float* __restrict__ out) {
    int wid = (blockIdx.x * 256 + threadIdx.x) >> 6;
    int l   = threadIdx.x & 63;
    if (wid >= N_NODES) return;
    const int q = l >> 4;
    const int r = l & 15;
    const bool act = (r < 10);
    const float ad = ad2[wid];
    const int j0 = __builtin_amdgcn_readfirstlane(offs[wid]);
    const int j1 = __builtin_amdgcn_readfirstlane(offs[wid + 1]);

    float den = 0.f;
    float4 acc = make_float4(0.f, 0.f, 0.f, 0.f);

    int c0 = csr[j0 + q];
    int c1 = csr[j0 + 4 + q];
    int c2 = csr[j0 + 8 + q];
    float  aA = as2[c0];
    float4 gA = act ? *(const float4*)&h2p[(unsigned)c0 * 48u + (unsigned)r * 4u]
                    : make_float4(0.f, 0.f, 0.f, 0.f);
    float  aB = as2[c1];
    float4 gB = act ? *(const float4*)&h2p[(unsigned)c1 * 48u + (unsigned)r * 4u]
                    : make_float4(0.f, 0.f, 0.f, 0.f);

    int j = j0;
    while (j + 4 <= j1) {
        float e = aA + ad;
        e = fmaxf(e, NEG_SLOPE * e);
        float xp = __expf(e);
        den += xp;
        acc.x = fmaf(xp, gA.x, acc.x);
        acc.y = fmaf(xp, gA.y, acc.y);
        acc.z = fmaf(xp, gA.z, acc.z);
        acc.w = fmaf(xp, gA.w, acc.w);
        aA = aB; gA = gB;
        aB = as2[c2];
        gB = act ? *(const float4*)&h2p[(unsigned)c2 * 48u + (unsigned)r * 4u]
                 : make_float4(0.f, 0.f, 0.f, 0.f);
        c2 = csr[j + 12 + q];
        j += 4;
    }
    const int rem = j1 - j;
    if (rem) {
        float e = aA + ad;
        e = fmaxf(e, NEG_SLOPE * e);
        float xp = (q < rem) ? __expf(e) : 0.f;
        den += xp;
        acc.x = fmaf(xp, gA.x, acc.x);
        acc.y = fmaf(xp, gA.y, acc.y);
        acc.z = fmaf(xp, gA.z, acc.z);
        acc.w = fmaf(xp, gA.w, acc.w);
    }
#pragma unroll
    for (int m = 16; m <= 32; m <<= 1) {
        den   += __shfl_xor(den,   m);
        acc.x += __shfl_xor(acc.x, m);
        acc.y += __shfl_xor(acc.y, m);
        acc.z += __shfl_xor(acc.z, m);
        acc.w += __shfl_xor(acc.w, m);
    }
    const float inv = 1.0f / den;
    float4 v = make_float4(0.f, 0.f, 0.f, 0.f);
    if (act) {
        float4 bv = *(const float4*)&b2[r * 4];
        v.x = fmaf(acc.x, inv, bv.x);
        v.y = fmaf(acc.y, inv, bv.y);
        v.z = fmaf(acc.z, inv, bv.z);
        v.w = fmaf(acc.w, inv, bv.w);
    }
    // log_softmax over 40 values spread on r=0..9 x 4 components
    float mx = act ? fmaxf(fmaxf(v.x, v.y), fmaxf(v.z, v.w)) : -1e30f;
#pragma unroll
    for (int m = 1; m <= 8; m <<= 1) mx = fmaxf(mx, __shfl_xor(mx, m));
    float s = act ? (__expf(v.x - mx) + __expf(v.y - mx) +
                     __expf(v.z - mx) + __expf(v.w - mx)) : 0.f;
#pragma unroll
    for (int m = 1; m <= 8; m <<= 1) s += __shfl_xor(s, m);
    const float lg = mx + __logf(s);
    if (act && q == 0) {
        float4 o;
        o.x = v.x - lg; o.y = v.y - lg; o.z = v.z - lg; o.w = v.w - lg;
        *(float4*)&out[(size_t)wid * 40 + r * 4] = o;
    }
}

// ---------------------------------------------------------------------------
extern "C" void kernel_launch(void* const* d_in, const int* in_sizes, int n_in,
                              void* d_out, int out_size, void* d_ws, size_t ws_size,
                              hipStream_t stream) {
    const float* x   = (const float*)d_in[0];
    const void*  ei  = d_in[1];
    const float* W1  = (const float*)d_in[2];
    const float* a1s = (const float*)d_in[3];
    const float* a1d = (const float*)d_in[4];
    const float* b1  = (const float*)d_in[5];
    const float* W2  = (const float*)d_in[6];
    const float* a2s = (const float*)d_in[7];
    const float* a2d = (const float*)d_in[8];
    const float* b2  = (const float*)d_in[9];
    float* out = (float*)d_out;

    // workspace layout (floats)
    float* fws = (float*)d_ws;
    float* h1  = fws + 0;                     // 3,200,000
    float* as1 = fws + 3200000;               //   400,000
    float* ad1 = fws + 3600000;               //   400,000
    float* h2p = fws + 4000000;               // 2,400,000 (stride 48)
    float* as2 = fws + 6400000;               //    50,000
    float* ad2 = fws + 6450000;               //    50,000
    int*   offs     = (int*)(fws + 6500000);  // 50,001
    int*   cursor   = offs + (N_NODES + 1);   // 50,000
    int*   csr      = cursor + N_NODES;       // 850,000 + 16 pad
    int*   partials = csr + E_TOT + 16;       // 49
    int*   flag     = partials + SCAN_BLOCKS; // 1
    int*   bcur     = flag + 1;               // 512
    unsigned int* stage = (unsigned int*)(bcur + BUCKETS);  // 850,000

    k_detect0<<<64, 256, 0, stream>>>((const unsigned int*)ei, flag, offs);

    int egrid = (E_TOT + 255) / 256;
    k_count<<<egrid, 256, 0, stream>>>(ei, flag, offs);
    k_scanA<<<SCAN_BLOCKS, 1024, 0, stream>>>(offs, partials);
    k_scanC<<<SCAN_BLOCKS, 1024, 0, stream>>>(offs, partials, cursor, bcur);

    int fagrid = (E_TOT + FA_CHUNK - 1) / FA_CHUNK;   // 52
    k_fillA<<<fagrid, FA_THREADS, 0, stream>>>(ei, flag, bcur, stage);
    k_fillB<<<BUCKETS - 1, 256, 0, stream>>>(stage, offs, cursor, csr);

    k1_transform<<<(N_NODES + 63) / 64, 256, 0, stream>>>(x, W1, a1s, a1d, h1, as1, ad1);

    int ngrid = (N_NODES + 3) / 4;
    k_agg1f<<<ngrid, 256, 0, stream>>>(h1, as1, ad1, offs, csr, b1,
                                       W2, a2s, a2d, h2p, as2, ad2);
    k_agg2<<<ngrid, 256, 0, stream>>>(h2p, as2, ad2, offs, csr, b2, out);
}